// Round 8
// baseline (1015.825 us; speedup 1.0000x reference)
//
#include <hip/hip_runtime.h>
#include <hip/hip_bf16.h>

typedef __bf16 bf16;
typedef __bf16 v8bf __attribute__((ext_vector_type(8)));
typedef float f32x4 __attribute__((ext_vector_type(4)));

#define NN 20000
#define EE 320000
#define FIN 256
#define D1 512
#define DOUT 128
#define ED 26

__device__ __forceinline__ float b2f(bf16 x) { return (float)x; }

__device__ __forceinline__ float2 ldbf2(const bf16* p) {
  unsigned int u;
  __builtin_memcpy(&u, p, 4);
  union { unsigned int i; float f; } lo, hi;
  lo.i = (u & 0xffffu) << 16;
  hi.i = u & 0xffff0000u;
  return make_float2(lo.f, hi.f);
}

__device__ __forceinline__ float2 ldf2(const float* p) {
  float2 t;
  __builtin_memcpy(&t, p, 8);
  return t;
}

// ---------------- small utils ----------------
__global__ void zero_k(int* __restrict__ p, int n) {
  int i = blockIdx.x * 256 + threadIdx.x;
  if (i < n) p[i] = 0;
}

// ---------------- edge_index dtype detect + convert ------------------------
// int64 -> all odd words of a positive-valued array are 0; int32 -> random ids.
__global__ void detflag_k(const int* __restrict__ ei32, int* __restrict__ flag) {
  int i = blockIdx.x * 256 + threadIdx.x;
  int v = (i < EE) ? ei32[2 * i + 1] : 0;
  unsigned long long b = __ballot(v != 0);
  if ((threadIdx.x & 63) == 0 && b) atomicOr(flag, 1);
}

__global__ void conv_k(const void* __restrict__ ei, const int* __restrict__ flag,
                       int* __restrict__ src, int* __restrict__ dst) {
  int i = blockIdx.x * 256 + threadIdx.x;
  if (i >= EE) return;
  int s, d;
  if (*flag == 0) {
    const long long* p = (const long long*)ei;
    s = (int)p[i];
    d = (int)p[EE + i];
  } else {
    const int* p = (const int*)ei;
    s = p[i];
    d = p[EE + i];
  }
  src[i] = min(max(s, 0), NN - 1);
  dst[i] = min(max(d, 0), NN - 1);
}

// ---------------- CSR build ----------------
__global__ void hist_k(const int* __restrict__ dst, int* __restrict__ deg, int n) {
  int e = blockIdx.x * 256 + threadIdx.x;
  if (e < n) atomicAdd(&deg[dst[e]], 1);
}

__global__ __launch_bounds__(1024) void scan_k(const int* __restrict__ deg,
                                               int* __restrict__ offs,
                                               int* __restrict__ cursor, int n) {
  __shared__ int lsum[1024];
  int t = threadIdx.x;
  const int CH = (n + 1023) / 1024;
  int base = t * CH;
  int s = 0;
  for (int i = 0; i < CH; i++) {
    int idx = base + i;
    if (idx < n) s += deg[idx];
  }
  lsum[t] = s;
  __syncthreads();
  for (int o = 1; o < 1024; o <<= 1) {
    int v = (t >= o) ? lsum[t - o] : 0;
    __syncthreads();
    lsum[t] += v;
    __syncthreads();
  }
  int ex = (t == 0) ? 0 : lsum[t - 1];
  for (int i = 0; i < CH; i++) {
    int idx = base + i;
    if (idx < n) {
      offs[idx] = ex;
      cursor[idx] = ex;
      ex += deg[idx];
    }
  }
  if (t == 1023) offs[n] = lsum[1023];
}

__global__ void scatter_k(const int* __restrict__ dst, int* __restrict__ cursor,
                          int* __restrict__ elist, int n) {
  int e = blockIdx.x * 256 + threadIdx.x;
  if (e < n) {
    int p = atomicAdd(&cursor[dst[e]], 1);
    if ((unsigned)p < (unsigned)EE) elist[p] = e;
  }
}

// ------- MFMA GEMM: out[M,Nc](TO) (+)= bf16(A[M,K]) @ bf16(B[K,Nc]) + bias
// A = f32 or bf16 (converted in-register); B, bias f32; out f32 or bf16.
// grid: (Nc/64, M/16), block 256 (4 waves, one 16x16 tile each)
template <typename TA, typename TO, bool ADD>
__global__ __launch_bounds__(256) void gemm_t(const TA* __restrict__ A,
                                              const float* __restrict__ B,
                                              const float* __restrict__ bias,
                                              TO* out, int Nc, int K) {
  int w = threadIdx.x >> 6;
  int l = threadIdx.x & 63;
  int quad = l >> 4;
  int mrow = blockIdx.y * 16 + (l & 15);
  int col = blockIdx.x * 64 + w * 16 + (l & 15);
  f32x4 acc = {0.f, 0.f, 0.f, 0.f};
  for (int k0 = 0; k0 < K; k0 += 32) {
    int ka = k0 + quad * 8;
    v8bf a, b;
    if constexpr (sizeof(TA) == 4) {
      const float* ap = (const float*)A + (size_t)mrow * K + ka;
#pragma unroll
      for (int j = 0; j < 8; j++) a[j] = (bf16)ap[j];
    } else {
      __builtin_memcpy(&a, (const bf16*)A + (size_t)mrow * K + ka, 16);
    }
#pragma unroll
    for (int j = 0; j < 8; j++) b[j] = (bf16)B[(size_t)(ka + j) * Nc + col];
    acc = __builtin_amdgcn_mfma_f32_16x16x32_bf16(a, b, acc, 0, 0, 0);
  }
  float bb = bias[col];
  int obase = blockIdx.y * 16 + quad * 4;
#pragma unroll
  for (int r = 0; r < 4; r++) {
    size_t idx = (size_t)(obase + r) * Nc + col;
    float v = acc[r] + bb;
    if (ADD) v += (float)out[idx];
    out[idx] = (TO)v;
  }
}

// ---------------- Layer-1 GATv2 aggregate (+bias), bf16 features ----------
// grid: NN x 256; wave w = head w; lane owns cols 128w+2l, +1.
// hout may alias xr (own-row read before own-row write) -> no __restrict__.
__global__ __launch_bounds__(256) void l1_agg(
    const bf16* __restrict__ xl, const bf16* xr,
    const float* __restrict__ eatt, const float* __restrict__ We,
    const float* __restrict__ att, const float* __restrict__ bias,
    const int* __restrict__ srcs, const int* __restrict__ offs,
    const int* __restrict__ elist, bf16* hout) {
  int node = blockIdx.x;
  int tid = threadIdx.x;
  int w = tid >> 6, l = tid & 63;
  int c = w * 128 + 2 * l;

  float w0[ED], w1[ED];
#pragma unroll
  for (int j = 0; j < ED; j++) {
    w0[j] = We[(size_t)j * D1 + c];
    w1[j] = We[(size_t)j * D1 + c + 1];
  }
  float a0 = att[c], a1 = att[c + 1];
  float2 rv = ldbf2(xr + (size_t)node * D1 + c);

  float mmax = -3.0e38f, den = 0.f, acc0 = 0.f, acc1 = 0.f;
  int i0 = offs[node], i1 = offs[node + 1];
  i0 = max(0, min(i0, EE));
  i1 = max(i0, min(i1, EE));
  for (int i = i0; i < i1; i++) {
    int e = elist[i];
    int s = srcs[e];
    const float* ear = eatt + (size_t)e * ED;
    float e0 = 0.f, e1 = 0.f;
#pragma unroll
    for (int j = 0; j < ED; j += 2) {
      float2 t = ldf2(ear + j);
      e0 += t.x * w0[j] + t.y * w0[j + 1];
      e1 += t.x * w1[j] + t.y * w1[j + 1];
    }
    float2 xv = ldbf2(xl + (size_t)s * D1 + c);
    float m0 = xv.x + rv.x + e0, m1 = xv.y + rv.y + e1;
    m0 = m0 > 0.f ? m0 : 0.2f * m0;
    m1 = m1 > 0.f ? m1 : 0.2f * m1;
    float al = m0 * a0 + m1 * a1;
#pragma unroll
    for (int o = 32; o; o >>= 1) al += __shfl_xor(al, o, 64);
    float nm = fmaxf(mmax, al);
    float sc = __expf(fminf(mmax - nm, 0.f));
    float p = __expf(fminf(al - nm, 0.f));
    den = den * sc + p;
    acc0 = acc0 * sc + p * xv.x;
    acc1 = acc1 * sc + p * xv.y;
    mmax = nm;
  }
  float inv = 1.f / (den + 1e-16f);
  hout[(size_t)node * D1 + c] = (bf16)(acc0 * inv + bias[c]);
  hout[(size_t)node * D1 + c + 1] = (bf16)(acc1 * inv + bias[c + 1]);
}

// ---------------- Layer-2 GATv2 aggregate (+bias), 1 head, f32 features ---
// grid: NN x 64; lane owns cols 2l, 2l+1. hout may alias xr.
__global__ __launch_bounds__(64) void l2_agg(
    const float* __restrict__ xl, const float* xr,
    const float* __restrict__ eatt, const float* __restrict__ We,
    const float* __restrict__ att, const float* __restrict__ bias,
    const int* __restrict__ srcs, const int* __restrict__ offs,
    const int* __restrict__ elist, float* hout) {
  int node = blockIdx.x;
  int l = threadIdx.x;
  int c = 2 * l;
  float w0[ED], w1[ED];
#pragma unroll
  for (int j = 0; j < ED; j++) {
    w0[j] = We[(size_t)j * DOUT + c];
    w1[j] = We[(size_t)j * DOUT + c + 1];
  }
  float a0 = att[c], a1 = att[c + 1];
  float2 rv = ldf2(xr + (size_t)node * DOUT + c);
  float mmax = -3.0e38f, den = 0.f, acc0 = 0.f, acc1 = 0.f;
  int i0 = offs[node], i1 = offs[node + 1];
  i0 = max(0, min(i0, EE));
  i1 = max(i0, min(i1, EE));
  for (int i = i0; i < i1; i++) {
    int e = elist[i];
    int s = srcs[e];
    const float* ear = eatt + (size_t)e * ED;
    float e0 = 0.f, e1 = 0.f;
#pragma unroll
    for (int j = 0; j < ED; j += 2) {
      float2 t = ldf2(ear + j);
      e0 += t.x * w0[j] + t.y * w0[j + 1];
      e1 += t.x * w1[j] + t.y * w1[j + 1];
    }
    float2 xv = ldf2(xl + (size_t)s * DOUT + c);
    float m0 = xv.x + rv.x + e0, m1 = xv.y + rv.y + e1;
    m0 = m0 > 0.f ? m0 : 0.2f * m0;
    m1 = m1 > 0.f ? m1 : 0.2f * m1;
    float al = m0 * a0 + m1 * a1;
#pragma unroll
    for (int o = 32; o; o >>= 1) al += __shfl_xor(al, o, 64);
    float nm = fmaxf(mmax, al);
    float sc = __expf(fminf(mmax - nm, 0.f));
    float p = __expf(fminf(al - nm, 0.f));
    den = den * sc + p;
    acc0 = acc0 * sc + p * xv.x;
    acc1 = acc1 * sc + p * xv.y;
    mmax = nm;
  }
  float inv = 1.f / (den + 1e-16f);
  hout[(size_t)node * DOUT + c] = acc0 * inv + bias[c];
  hout[(size_t)node * DOUT + c + 1] = acc1 * inv + bias[c + 1];
}

// ---------------- LayerNorm(512) + ELU, in place (bf16) --------------------
__global__ __launch_bounds__(256) void lnelu_k(bf16* buf,
                                               const float* __restrict__ g,
                                               const float* __restrict__ be) {
  int node = blockIdx.x, tid = threadIdx.x;
  int w = tid >> 6, l = tid & 63;
  int c = tid * 2;
  float2 o = ldbf2(buf + (size_t)node * D1 + c);
  float s1 = o.x + o.y, s2 = o.x * o.x + o.y * o.y;
#pragma unroll
  for (int of = 32; of; of >>= 1) {
    s1 += __shfl_xor(s1, of, 64);
    s2 += __shfl_xor(s2, of, 64);
  }
  __shared__ float r1[4], r2[4];
  if (l == 0) { r1[w] = s1; r2[w] = s2; }
  __syncthreads();
  float S1 = r1[0] + r1[1] + r1[2] + r1[3];
  float S2 = r2[0] + r2[1] + r2[2] + r2[3];
  float mu = S1 * (1.f / 512.f);
  float var = fmaxf(S2 * (1.f / 512.f) - mu * mu, 0.f);
  float rs = rsqrtf(var + 1e-5f);
  float y0 = (o.x - mu) * rs * g[c] + be[c];
  float y1 = (o.y - mu) * rs * g[c + 1] + be[c + 1];
  y0 = y0 > 0.f ? y0 : __expf(fminf(y0, 0.f)) - 1.f;
  y1 = y1 > 0.f ? y1 : __expf(fminf(y1, 0.f)) - 1.f;
  buf[(size_t)node * D1 + c] = (bf16)y0;
  buf[(size_t)node * D1 + c + 1] = (bf16)y1;
}

// ---------------- final LayerNorm(128): f32 -> f32 d_out -------------------
__global__ __launch_bounds__(64) void ln128_k(const float* __restrict__ buf,
                                              const float* __restrict__ g,
                                              const float* __restrict__ be,
                                              float* __restrict__ outp) {
  int node = blockIdx.x, l = threadIdx.x;
  int c = 2 * l;
  float2 o = ldf2(buf + (size_t)node * DOUT + c);
  float s1 = o.x + o.y, s2 = o.x * o.x + o.y * o.y;
#pragma unroll
  for (int of = 32; of; of >>= 1) {
    s1 += __shfl_xor(s1, of, 64);
    s2 += __shfl_xor(s2, of, 64);
  }
  float mu = s1 * (1.f / 128.f);
  float var = fmaxf(s2 * (1.f / 128.f) - mu * mu, 0.f);
  float rs = rsqrtf(var + 1e-5f);
  outp[(size_t)node * DOUT + c] = (o.x - mu) * rs * g[c] + be[c];
  outp[(size_t)node * DOUT + c + 1] = (o.y - mu) * rs * g[c + 1] + be[c + 1];
}

extern "C" void kernel_launch(void* const* d_in, const int* in_sizes, int n_in,
                              void* d_out, int out_size, void* d_ws, size_t ws_size,
                              hipStream_t stream) {
  const float* x = (const float*)d_in[0];
  const void* ei = d_in[1];
  const float* eattr = (const float*)d_in[2];
  const float* W1l = (const float*)d_in[3];
  const float* b1l = (const float*)d_in[4];
  const float* W1r = (const float*)d_in[5];
  const float* b1r = (const float*)d_in[6];
  const float* We1 = (const float*)d_in[7];
  const float* att1 = (const float*)d_in[8];
  const float* bias1 = (const float*)d_in[9];
  const float* Wsk1 = (const float*)d_in[10];
  const float* bsk1 = (const float*)d_in[11];
  const float* g1 = (const float*)d_in[12];
  const float* be1 = (const float*)d_in[13];
  const float* W2l = (const float*)d_in[14];
  const float* b2l = (const float*)d_in[15];
  const float* W2r = (const float*)d_in[16];
  const float* b2r = (const float*)d_in[17];
  const float* We2 = (const float*)d_in[18];
  const float* att2 = (const float*)d_in[19];
  const float* bias2 = (const float*)d_in[20];
  const float* Wsk2 = (const float*)d_in[21];
  const float* bsk2 = (const float*)d_in[22];
  const float* g2 = (const float*)d_in[23];
  const float* be2 = (const float*)d_in[24];

  // workspace carve (256B aligned) -- total ~46 MiB
  char* p = (char*)d_ws;
  size_t off = 0;
  auto carve = [&](size_t bytes) {
    void* r = p + off;
    off = (off + bytes + 255) & ~(size_t)255;
    return r;
  };
  int* flag = (int*)carve(sizeof(int));
  int* srcD = (int*)carve(EE * sizeof(int));
  int* dstD = (int*)carve(EE * sizeof(int));
  int* deg = (int*)carve(NN * sizeof(int));
  int* offs = (int*)carve((NN + 1) * sizeof(int));
  int* cursor = (int*)carve(NN * sizeof(int));
  int* elist = (int*)carve(EE * sizeof(int));
  bf16* bufA = (bf16*)carve((size_t)NN * D1 * 2);  // xl1 (bf16); then f32 x2l/x2r
  bf16* bufB = (bf16*)carve((size_t)NN * D1 * 2);  // xr1 -> agg -> +skip -> h (bf16)

  float* q0 = (float*)bufA;              // x2l (f32, 10.24MB)
  float* q1 = q0 + (size_t)NN * DOUT;    // x2r (f32, 10.24MB) -> agg2 -> +skip2

  // edge_index detect + convert to clean int32 src/dst
  zero_k<<<1, 256, 0, stream>>>(flag, 1);
  detflag_k<<<(EE + 255) / 256, 256, 0, stream>>>((const int*)ei, flag);
  conv_k<<<(EE + 255) / 256, 256, 0, stream>>>(ei, flag, srcD, dstD);

  // CSR build (by dst)
  zero_k<<<(NN + 255) / 256, 256, 0, stream>>>(deg, NN);
  hist_k<<<(EE + 255) / 256, 256, 0, stream>>>(dstD, deg, EE);
  scan_k<<<1, 1024, 0, stream>>>(deg, offs, cursor, NN);
  scatter_k<<<(EE + 255) / 256, 256, 0, stream>>>(dstD, cursor, elist, EE);

  // layer-1: xl = x@W1l+b1l, xr = x@W1r+b1r  (f32 in, bf16 out)
  gemm_t<float, bf16, false><<<dim3(D1 / 64, NN / 16), 256, 0, stream>>>(x, W1l, b1l, bufA, D1, FIN);
  gemm_t<float, bf16, false><<<dim3(D1 / 64, NN / 16), 256, 0, stream>>>(x, W1r, b1r, bufB, D1, FIN);
  // aggregate (+bias1) in place over xr
  l1_agg<<<NN, 256, 0, stream>>>(bufA, bufB, eattr, We1, att1, bias1,
                                 srcD, offs, elist, bufB);
  // += x@Wskip1 + bskip1
  gemm_t<float, bf16, true><<<dim3(D1 / 64, NN / 16), 256, 0, stream>>>(x, Wsk1, bsk1, bufB, D1, FIN);
  // h = ELU(LN(bufB)) in place (bf16)
  lnelu_k<<<NN, 256, 0, stream>>>(bufB, g1, be1);

  // layer-2: x2l = h@W2l+b2l, x2r = h@W2r+b2r  (bf16 A, f32 out)
  gemm_t<bf16, float, false><<<dim3(DOUT / 64, NN / 16), 256, 0, stream>>>(bufB, W2l, b2l, q0, DOUT, D1);
  gemm_t<bf16, float, false><<<dim3(DOUT / 64, NN / 16), 256, 0, stream>>>(bufB, W2r, b2r, q1, DOUT, D1);
  // aggregate (+bias2) in place over x2r (f32)
  l2_agg<<<NN, 64, 0, stream>>>(q0, q1, eattr, We2, att2, bias2,
                                srcD, offs, elist, q1);
  // += h@Wskip2 + bskip2 (f32 accumulate)
  gemm_t<bf16, float, true><<<dim3(DOUT / 64, NN / 16), 256, 0, stream>>>(bufB, Wsk2, bsk2, q1, DOUT, D1);
  // final LN -> f32 d_out
  ln128_k<<<NN, 64, 0, stream>>>(q1, g2, be2, (float*)d_out);

  (void)in_sizes; (void)n_in; (void)out_size; (void)ws_size;
}

// Round 9
// 1006.013 us; speedup vs baseline: 1.0098x; 1.0098x over previous
//
#include <hip/hip_runtime.h>
#include <hip/hip_bf16.h>

typedef __bf16 bf16;
typedef __bf16 v8bf __attribute__((ext_vector_type(8)));
typedef float f32x4 __attribute__((ext_vector_type(4)));

#define NN 20000
#define EE 320000
#define FIN 256
#define D1 512
#define DOUT 128
#define ED 26

__device__ __forceinline__ float b2f(bf16 x) { return (float)x; }

__device__ __forceinline__ float2 ldbf2(const bf16* p) {
  unsigned int u;
  __builtin_memcpy(&u, p, 4);
  union { unsigned int i; float f; } lo, hi;
  lo.i = (u & 0xffffu) << 16;
  hi.i = u & 0xffff0000u;
  return make_float2(lo.f, hi.f);
}

__device__ __forceinline__ float2 ldf2(const float* p) {
  float2 t;
  __builtin_memcpy(&t, p, 8);
  return t;
}

// ---------------- small utils ----------------
__global__ void zero_k(int* __restrict__ p, int n) {
  int i = blockIdx.x * 256 + threadIdx.x;
  if (i < n) p[i] = 0;
}

// ---------------- edge_index dtype detect + convert ------------------------
__global__ void detflag_k(const int* __restrict__ ei32, int* __restrict__ flag) {
  int i = blockIdx.x * 256 + threadIdx.x;
  int v = (i < EE) ? ei32[2 * i + 1] : 0;
  unsigned long long b = __ballot(v != 0);
  if ((threadIdx.x & 63) == 0 && b) atomicOr(flag, 1);
}

__global__ void conv_k(const void* __restrict__ ei, const int* __restrict__ flag,
                       int* __restrict__ src, int* __restrict__ dst) {
  int i = blockIdx.x * 256 + threadIdx.x;
  if (i >= EE) return;
  int s, d;
  if (*flag == 0) {
    const long long* p = (const long long*)ei;
    s = (int)p[i];
    d = (int)p[EE + i];
  } else {
    const int* p = (const int*)ei;
    s = p[i];
    d = p[EE + i];
  }
  src[i] = min(max(s, 0), NN - 1);
  dst[i] = min(max(d, 0), NN - 1);
}

// ---------------- CSR build ----------------
__global__ void hist_k(const int* __restrict__ dst, int* __restrict__ deg, int n) {
  int e = blockIdx.x * 256 + threadIdx.x;
  if (e < n) atomicAdd(&deg[dst[e]], 1);
}

__global__ __launch_bounds__(1024) void scan_k(const int* __restrict__ deg,
                                               int* __restrict__ offs,
                                               int* __restrict__ cursor, int n) {
  __shared__ int lsum[1024];
  int t = threadIdx.x;
  const int CH = (n + 1023) / 1024;
  int base = t * CH;
  int s = 0;
  for (int i = 0; i < CH; i++) {
    int idx = base + i;
    if (idx < n) s += deg[idx];
  }
  lsum[t] = s;
  __syncthreads();
  for (int o = 1; o < 1024; o <<= 1) {
    int v = (t >= o) ? lsum[t - o] : 0;
    __syncthreads();
    lsum[t] += v;
    __syncthreads();
  }
  int ex = (t == 0) ? 0 : lsum[t - 1];
  for (int i = 0; i < CH; i++) {
    int idx = base + i;
    if (idx < n) {
      offs[idx] = ex;
      cursor[idx] = ex;
      ex += deg[idx];
    }
  }
  if (t == 1023) offs[n] = lsum[1023];
}

__global__ void scatter_k(const int* __restrict__ dst, int* __restrict__ cursor,
                          int* __restrict__ elist, int n) {
  int e = blockIdx.x * 256 + threadIdx.x;
  if (e < n) {
    int p = atomicAdd(&cursor[dst[e]], 1);
    if ((unsigned)p < (unsigned)EE) elist[p] = e;
  }
}

// ------- MFMA GEMM: out[M,Nc](TO) (+)= bf16(A[M,K]) @ bf16(B[K,Nc]) + bias
template <typename TA, typename TO, bool ADD>
__global__ __launch_bounds__(256) void gemm_t(const TA* __restrict__ A,
                                              const float* __restrict__ B,
                                              const float* __restrict__ bias,
                                              TO* out, int Nc, int K) {
  int w = threadIdx.x >> 6;
  int l = threadIdx.x & 63;
  int quad = l >> 4;
  int mrow = blockIdx.y * 16 + (l & 15);
  int col = blockIdx.x * 64 + w * 16 + (l & 15);
  f32x4 acc = {0.f, 0.f, 0.f, 0.f};
  for (int k0 = 0; k0 < K; k0 += 32) {
    int ka = k0 + quad * 8;
    v8bf a, b;
    if constexpr (sizeof(TA) == 4) {
      const float* ap = (const float*)A + (size_t)mrow * K + ka;
#pragma unroll
      for (int j = 0; j < 8; j++) a[j] = (bf16)ap[j];
    } else {
      __builtin_memcpy(&a, (const bf16*)A + (size_t)mrow * K + ka, 16);
    }
#pragma unroll
    for (int j = 0; j < 8; j++) b[j] = (bf16)B[(size_t)(ka + j) * Nc + col];
    acc = __builtin_amdgcn_mfma_f32_16x16x32_bf16(a, b, acc, 0, 0, 0);
  }
  float bb = bias[col];
  int obase = blockIdx.y * 16 + quad * 4;
#pragma unroll
  for (int r = 0; r < 4; r++) {
    size_t idx = (size_t)(obase + r) * Nc + col;
    float v = acc[r] + bb;
    if (ADD) v += (float)out[idx];
    out[idx] = (TO)v;
  }
}

// ---------------- Layer-1 GATv2 aggregate (+bias), bf16 features ----------
// grid: NN x 256; wave w = head w; lane owns cols 128w+2l, +1.
// __launch_bounds__(256,4): VGPR budget 128 so the 52-reg We hoist stays
// registerized (round-8 run showed VGPR=40 -> We reloaded every edge).
// Unroll-2: two independent online-softmax chains, merged at the end.
__global__ __launch_bounds__(256, 4) void l1_agg(
    const bf16* __restrict__ xl, const bf16* xr,
    const float* __restrict__ eatt, const float* __restrict__ We,
    const float* __restrict__ att, const float* __restrict__ bias,
    const int* __restrict__ srcs, const int* __restrict__ offs,
    const int* __restrict__ elist, bf16* hout) {
  int node = blockIdx.x;
  int tid = threadIdx.x;
  int w = tid >> 6, l = tid & 63;
  int c = w * 128 + 2 * l;

  float w0[ED], w1[ED];
#pragma unroll
  for (int j = 0; j < ED; j++) {
    w0[j] = We[(size_t)j * D1 + c];
    w1[j] = We[(size_t)j * D1 + c + 1];
  }
  float a0 = att[c], a1 = att[c + 1];
  float2 rv = ldbf2(xr + (size_t)node * D1 + c);

  float mA = -3.0e38f, dA = 0.f, pA0 = 0.f, pA1 = 0.f;
  float mB = -3.0e38f, dB = 0.f, pB0 = 0.f, pB1 = 0.f;
  int i0 = offs[node], i1 = offs[node + 1];
  i0 = max(0, min(i0, EE));
  i1 = max(i0, min(i1, EE));
  int i = i0;
  for (; i + 1 < i1; i += 2) {
    int eA = __builtin_amdgcn_readfirstlane(elist[i]);
    int eB = __builtin_amdgcn_readfirstlane(elist[i + 1]);
    int sA = __builtin_amdgcn_readfirstlane(srcs[eA]);
    int sB = __builtin_amdgcn_readfirstlane(srcs[eB]);
    const float* earA = eatt + (size_t)eA * ED;
    const float* earB = eatt + (size_t)eB * ED;
    float eA0 = 0.f, eA1 = 0.f, eB0 = 0.f, eB1 = 0.f;
#pragma unroll
    for (int j = 0; j < ED; j += 2) {
      float2 tA = ldf2(earA + j);
      float2 tB = ldf2(earB + j);
      eA0 += tA.x * w0[j] + tA.y * w0[j + 1];
      eA1 += tA.x * w1[j] + tA.y * w1[j + 1];
      eB0 += tB.x * w0[j] + tB.y * w0[j + 1];
      eB1 += tB.x * w1[j] + tB.y * w1[j + 1];
    }
    float2 xvA = ldbf2(xl + (size_t)sA * D1 + c);
    float2 xvB = ldbf2(xl + (size_t)sB * D1 + c);
    float mA0 = xvA.x + rv.x + eA0, mA1 = xvA.y + rv.y + eA1;
    float mB0 = xvB.x + rv.x + eB0, mB1 = xvB.y + rv.y + eB1;
    mA0 = mA0 > 0.f ? mA0 : 0.2f * mA0;
    mA1 = mA1 > 0.f ? mA1 : 0.2f * mA1;
    mB0 = mB0 > 0.f ? mB0 : 0.2f * mB0;
    mB1 = mB1 > 0.f ? mB1 : 0.2f * mB1;
    float alA = mA0 * a0 + mA1 * a1;
    float alB = mB0 * a0 + mB1 * a1;
#pragma unroll
    for (int o = 32; o; o >>= 1) {
      alA += __shfl_xor(alA, o, 64);
      alB += __shfl_xor(alB, o, 64);
    }
    float nmA = fmaxf(mA, alA);
    float scA = __expf(fminf(mA - nmA, 0.f));
    float prA = __expf(fminf(alA - nmA, 0.f));
    dA = dA * scA + prA;
    pA0 = pA0 * scA + prA * xvA.x;
    pA1 = pA1 * scA + prA * xvA.y;
    mA = nmA;
    float nmB = fmaxf(mB, alB);
    float scB = __expf(fminf(mB - nmB, 0.f));
    float prB = __expf(fminf(alB - nmB, 0.f));
    dB = dB * scB + prB;
    pB0 = pB0 * scB + prB * xvB.x;
    pB1 = pB1 * scB + prB * xvB.y;
    mB = nmB;
  }
  if (i < i1) {
    int e = __builtin_amdgcn_readfirstlane(elist[i]);
    int s = __builtin_amdgcn_readfirstlane(srcs[e]);
    const float* ear = eatt + (size_t)e * ED;
    float e0 = 0.f, e1 = 0.f;
#pragma unroll
    for (int j = 0; j < ED; j += 2) {
      float2 t = ldf2(ear + j);
      e0 += t.x * w0[j] + t.y * w0[j + 1];
      e1 += t.x * w1[j] + t.y * w1[j + 1];
    }
    float2 xv = ldbf2(xl + (size_t)s * D1 + c);
    float m0 = xv.x + rv.x + e0, m1 = xv.y + rv.y + e1;
    m0 = m0 > 0.f ? m0 : 0.2f * m0;
    m1 = m1 > 0.f ? m1 : 0.2f * m1;
    float al = m0 * a0 + m1 * a1;
#pragma unroll
    for (int o = 32; o; o >>= 1) al += __shfl_xor(al, o, 64);
    float nm = fmaxf(mA, al);
    float sc = __expf(fminf(mA - nm, 0.f));
    float pr = __expf(fminf(al - nm, 0.f));
    dA = dA * sc + pr;
    pA0 = pA0 * sc + pr * xv.x;
    pA1 = pA1 * sc + pr * xv.y;
    mA = nm;
  }
  // merge chains A,B
  float m = fmaxf(mA, mB);
  float sA = __expf(fminf(mA - m, 0.f));
  float sB = __expf(fminf(mB - m, 0.f));
  float den = dA * sA + dB * sB;
  float acc0 = pA0 * sA + pB0 * sB;
  float acc1 = pA1 * sA + pB1 * sB;

  float inv = 1.f / (den + 1e-16f);
  hout[(size_t)node * D1 + c] = (bf16)(acc0 * inv + bias[c]);
  hout[(size_t)node * D1 + c + 1] = (bf16)(acc1 * inv + bias[c + 1]);
}

// ---------------- Layer-2 GATv2 aggregate (+bias), 1 head, f32 features ---
// grid: NN x 64; lane owns cols 2l, 2l+1. hout may alias xr.
__global__ __launch_bounds__(64, 4) void l2_agg(
    const float* __restrict__ xl, const float* xr,
    const float* __restrict__ eatt, const float* __restrict__ We,
    const float* __restrict__ att, const float* __restrict__ bias,
    const int* __restrict__ srcs, const int* __restrict__ offs,
    const int* __restrict__ elist, float* hout) {
  int node = blockIdx.x;
  int l = threadIdx.x;
  int c = 2 * l;
  float w0[ED], w1[ED];
#pragma unroll
  for (int j = 0; j < ED; j++) {
    w0[j] = We[(size_t)j * DOUT + c];
    w1[j] = We[(size_t)j * DOUT + c + 1];
  }
  float a0 = att[c], a1 = att[c + 1];
  float2 rv = ldf2(xr + (size_t)node * DOUT + c);
  float mA = -3.0e38f, dA = 0.f, pA0 = 0.f, pA1 = 0.f;
  float mB = -3.0e38f, dB = 0.f, pB0 = 0.f, pB1 = 0.f;
  int i0 = offs[node], i1 = offs[node + 1];
  i0 = max(0, min(i0, EE));
  i1 = max(i0, min(i1, EE));
  int i = i0;
  for (; i + 1 < i1; i += 2) {
    int eA = __builtin_amdgcn_readfirstlane(elist[i]);
    int eB = __builtin_amdgcn_readfirstlane(elist[i + 1]);
    int sA = __builtin_amdgcn_readfirstlane(srcs[eA]);
    int sB = __builtin_amdgcn_readfirstlane(srcs[eB]);
    const float* earA = eatt + (size_t)eA * ED;
    const float* earB = eatt + (size_t)eB * ED;
    float eA0 = 0.f, eA1 = 0.f, eB0 = 0.f, eB1 = 0.f;
#pragma unroll
    for (int j = 0; j < ED; j += 2) {
      float2 tA = ldf2(earA + j);
      float2 tB = ldf2(earB + j);
      eA0 += tA.x * w0[j] + tA.y * w0[j + 1];
      eA1 += tA.x * w1[j] + tA.y * w1[j + 1];
      eB0 += tB.x * w0[j] + tB.y * w0[j + 1];
      eB1 += tB.x * w1[j] + tB.y * w1[j + 1];
    }
    float2 xvA = ldf2(xl + (size_t)sA * DOUT + c);
    float2 xvB = ldf2(xl + (size_t)sB * DOUT + c);
    float mA0 = xvA.x + rv.x + eA0, mA1 = xvA.y + rv.y + eA1;
    float mB0 = xvB.x + rv.x + eB0, mB1 = xvB.y + rv.y + eB1;
    mA0 = mA0 > 0.f ? mA0 : 0.2f * mA0;
    mA1 = mA1 > 0.f ? mA1 : 0.2f * mA1;
    mB0 = mB0 > 0.f ? mB0 : 0.2f * mB0;
    mB1 = mB1 > 0.f ? mB1 : 0.2f * mB1;
    float alA = mA0 * a0 + mA1 * a1;
    float alB = mB0 * a0 + mB1 * a1;
#pragma unroll
    for (int o = 32; o; o >>= 1) {
      alA += __shfl_xor(alA, o, 64);
      alB += __shfl_xor(alB, o, 64);
    }
    float nmA = fmaxf(mA, alA);
    float scA = __expf(fminf(mA - nmA, 0.f));
    float prA = __expf(fminf(alA - nmA, 0.f));
    dA = dA * scA + prA;
    pA0 = pA0 * scA + prA * xvA.x;
    pA1 = pA1 * scA + prA * xvA.y;
    mA = nmA;
    float nmB = fmaxf(mB, alB);
    float scB = __expf(fminf(mB - nmB, 0.f));
    float prB = __expf(fminf(alB - nmB, 0.f));
    dB = dB * scB + prB;
    pB0 = pB0 * scB + prB * xvB.x;
    pB1 = pB1 * scB + prB * xvB.y;
    mB = nmB;
  }
  if (i < i1) {
    int e = __builtin_amdgcn_readfirstlane(elist[i]);
    int s = __builtin_amdgcn_readfirstlane(srcs[e]);
    const float* ear = eatt + (size_t)e * ED;
    float e0 = 0.f, e1 = 0.f;
#pragma unroll
    for (int j = 0; j < ED; j += 2) {
      float2 t = ldf2(ear + j);
      e0 += t.x * w0[j] + t.y * w0[j + 1];
      e1 += t.x * w1[j] + t.y * w1[j + 1];
    }
    float2 xv = ldf2(xl + (size_t)s * DOUT + c);
    float m0 = xv.x + rv.x + e0, m1 = xv.y + rv.y + e1;
    m0 = m0 > 0.f ? m0 : 0.2f * m0;
    m1 = m1 > 0.f ? m1 : 0.2f * m1;
    float al = m0 * a0 + m1 * a1;
#pragma unroll
    for (int o = 32; o; o >>= 1) al += __shfl_xor(al, o, 64);
    float nm = fmaxf(mA, al);
    float sc = __expf(fminf(mA - nm, 0.f));
    float pr = __expf(fminf(al - nm, 0.f));
    dA = dA * sc + pr;
    pA0 = pA0 * sc + pr * xv.x;
    pA1 = pA1 * sc + pr * xv.y;
    mA = nm;
  }
  float m = fmaxf(mA, mB);
  float sA = __expf(fminf(mA - m, 0.f));
  float sB = __expf(fminf(mB - m, 0.f));
  float den = dA * sA + dB * sB;
  float acc0 = pA0 * sA + pB0 * sB;
  float acc1 = pA1 * sA + pB1 * sB;
  float inv = 1.f / (den + 1e-16f);
  hout[(size_t)node * DOUT + c] = acc0 * inv + bias[c];
  hout[(size_t)node * DOUT + c + 1] = acc1 * inv + bias[c + 1];
}

// ---------------- LayerNorm(512) + ELU, in place (bf16) --------------------
__global__ __launch_bounds__(256) void lnelu_k(bf16* buf,
                                               const float* __restrict__ g,
                                               const float* __restrict__ be) {
  int node = blockIdx.x, tid = threadIdx.x;
  int w = tid >> 6, l = tid & 63;
  int c = tid * 2;
  float2 o = ldbf2(buf + (size_t)node * D1 + c);
  float s1 = o.x + o.y, s2 = o.x * o.x + o.y * o.y;
#pragma unroll
  for (int of = 32; of; of >>= 1) {
    s1 += __shfl_xor(s1, of, 64);
    s2 += __shfl_xor(s2, of, 64);
  }
  __shared__ float r1[4], r2[4];
  if (l == 0) { r1[w] = s1; r2[w] = s2; }
  __syncthreads();
  float S1 = r1[0] + r1[1] + r1[2] + r1[3];
  float S2 = r2[0] + r2[1] + r2[2] + r2[3];
  float mu = S1 * (1.f / 512.f);
  float var = fmaxf(S2 * (1.f / 512.f) - mu * mu, 0.f);
  float rs = rsqrtf(var + 1e-5f);
  float y0 = (o.x - mu) * rs * g[c] + be[c];
  float y1 = (o.y - mu) * rs * g[c + 1] + be[c + 1];
  y0 = y0 > 0.f ? y0 : __expf(fminf(y0, 0.f)) - 1.f;
  y1 = y1 > 0.f ? y1 : __expf(fminf(y1, 0.f)) - 1.f;
  buf[(size_t)node * D1 + c] = (bf16)y0;
  buf[(size_t)node * D1 + c + 1] = (bf16)y1;
}

// ---------------- final LayerNorm(128): f32 -> f32 d_out -------------------
__global__ __launch_bounds__(64) void ln128_k(const float* __restrict__ buf,
                                              const float* __restrict__ g,
                                              const float* __restrict__ be,
                                              float* __restrict__ outp) {
  int node = blockIdx.x, l = threadIdx.x;
  int c = 2 * l;
  float2 o = ldf2(buf + (size_t)node * DOUT + c);
  float s1 = o.x + o.y, s2 = o.x * o.x + o.y * o.y;
#pragma unroll
  for (int of = 32; of; of >>= 1) {
    s1 += __shfl_xor(s1, of, 64);
    s2 += __shfl_xor(s2, of, 64);
  }
  float mu = s1 * (1.f / 128.f);
  float var = fmaxf(s2 * (1.f / 128.f) - mu * mu, 0.f);
  float rs = rsqrtf(var + 1e-5f);
  outp[(size_t)node * DOUT + c] = (o.x - mu) * rs * g[c] + be[c];
  outp[(size_t)node * DOUT + c + 1] = (o.y - mu) * rs * g[c + 1] + be[c + 1];
}

extern "C" void kernel_launch(void* const* d_in, const int* in_sizes, int n_in,
                              void* d_out, int out_size, void* d_ws, size_t ws_size,
                              hipStream_t stream) {
  const float* x = (const float*)d_in[0];
  const void* ei = d_in[1];
  const float* eattr = (const float*)d_in[2];
  const float* W1l = (const float*)d_in[3];
  const float* b1l = (const float*)d_in[4];
  const float* W1r = (const float*)d_in[5];
  const float* b1r = (const float*)d_in[6];
  const float* We1 = (const float*)d_in[7];
  const float* att1 = (const float*)d_in[8];
  const float* bias1 = (const float*)d_in[9];
  const float* Wsk1 = (const float*)d_in[10];
  const float* bsk1 = (const float*)d_in[11];
  const float* g1 = (const float*)d_in[12];
  const float* be1 = (const float*)d_in[13];
  const float* W2l = (const float*)d_in[14];
  const float* b2l = (const float*)d_in[15];
  const float* W2r = (const float*)d_in[16];
  const float* b2r = (const float*)d_in[17];
  const float* We2 = (const float*)d_in[18];
  const float* att2 = (const float*)d_in[19];
  const float* bias2 = (const float*)d_in[20];
  const float* Wsk2 = (const float*)d_in[21];
  const float* bsk2 = (const float*)d_in[22];
  const float* g2 = (const float*)d_in[23];
  const float* be2 = (const float*)d_in[24];

  // workspace carve (256B aligned) -- total ~46 MiB
  char* p = (char*)d_ws;
  size_t off = 0;
  auto carve = [&](size_t bytes) {
    void* r = p + off;
    off = (off + bytes + 255) & ~(size_t)255;
    return r;
  };
  int* flag = (int*)carve(sizeof(int));
  int* srcD = (int*)carve(EE * sizeof(int));
  int* dstD = (int*)carve(EE * sizeof(int));
  int* deg = (int*)carve(NN * sizeof(int));
  int* offs = (int*)carve((NN + 1) * sizeof(int));
  int* cursor = (int*)carve(NN * sizeof(int));
  int* elist = (int*)carve(EE * sizeof(int));
  bf16* bufA = (bf16*)carve((size_t)NN * D1 * 2);  // xl1 (bf16); then f32 x2l/x2r
  bf16* bufB = (bf16*)carve((size_t)NN * D1 * 2);  // xr1 -> agg -> +skip -> h (bf16)

  float* q0 = (float*)bufA;              // x2l (f32)
  float* q1 = q0 + (size_t)NN * DOUT;    // x2r (f32) -> agg2 -> +skip2

  // edge_index detect + convert
  zero_k<<<1, 256, 0, stream>>>(flag, 1);
  detflag_k<<<(EE + 255) / 256, 256, 0, stream>>>((const int*)ei, flag);
  conv_k<<<(EE + 255) / 256, 256, 0, stream>>>(ei, flag, srcD, dstD);

  // CSR build (by dst)
  zero_k<<<(NN + 255) / 256, 256, 0, stream>>>(deg, NN);
  hist_k<<<(EE + 255) / 256, 256, 0, stream>>>(dstD, deg, EE);
  scan_k<<<1, 1024, 0, stream>>>(deg, offs, cursor, NN);
  scatter_k<<<(EE + 255) / 256, 256, 0, stream>>>(dstD, cursor, elist, EE);

  // layer-1: xl = x@W1l+b1l, xr = x@W1r+b1r  (f32 in, bf16 out)
  gemm_t<float, bf16, false><<<dim3(D1 / 64, NN / 16), 256, 0, stream>>>(x, W1l, b1l, bufA, D1, FIN);
  gemm_t<float, bf16, false><<<dim3(D1 / 64, NN / 16), 256, 0, stream>>>(x, W1r, b1r, bufB, D1, FIN);
  l1_agg<<<NN, 256, 0, stream>>>(bufA, bufB, eattr, We1, att1, bias1,
                                 srcD, offs, elist, bufB);
  gemm_t<float, bf16, true><<<dim3(D1 / 64, NN / 16), 256, 0, stream>>>(x, Wsk1, bsk1, bufB, D1, FIN);
  lnelu_k<<<NN, 256, 0, stream>>>(bufB, g1, be1);

  // layer-2: x2l = h@W2l+b2l, x2r = h@W2r+b2r  (bf16 A, f32 out)
  gemm_t<bf16, float, false><<<dim3(DOUT / 64, NN / 16), 256, 0, stream>>>(bufB, W2l, b2l, q0, DOUT, D1);
  gemm_t<bf16, float, false><<<dim3(DOUT / 64, NN / 16), 256, 0, stream>>>(bufB, W2r, b2r, q1, DOUT, D1);
  l2_agg<<<NN, 64, 0, stream>>>(q0, q1, eattr, We2, att2, bias2,
                                srcD, offs, elist, q1);
  gemm_t<bf16, float, true><<<dim3(DOUT / 64, NN / 16), 256, 0, stream>>>(bufB, Wsk2, bsk2, q1, DOUT, D1);
  ln128_k<<<NN, 64, 0, stream>>>(q1, g2, be2, (float*)d_out);

  (void)in_sizes; (void)n_in; (void)out_size; (void)ws_size;
}